// Round 9
// baseline (1252.990 us; speedup 1.0000x reference)
//
#include <hip/hip_runtime.h>
#include <math.h>

// Problem constants
#define NCASES   16
#define NPTS_BIG 65536
#define OUT_B    4096

typedef __attribute__((ext_vector_type(8))) short  short8;   // 8 bf16 = 4 VGPR (MFMA A/B frag)
typedef __attribute__((ext_vector_type(4))) float  floatx4;  // MFMA C/D frag

__device__ __forceinline__ float silu_f(float x) {
    return x * __builtin_amdgcn_rcpf(1.0f + __expf(-x));
}

// RNE fp32->bf16 (one-time prep only)
__device__ __forceinline__ unsigned f2bf_hi(float x) {
    unsigned u = __float_as_uint(x);
    return u + 0x7FFFu + ((u >> 16) & 1u);
}
__device__ __forceinline__ unsigned short f2bf(float x) {
    return (unsigned short)(f2bf_hi(x) >> 16);
}
// RTZ pack: two f32 -> two bf16 in one v_perm (hot loop)
__device__ __forceinline__ unsigned pk2bf_rtz(float lo, float hi) {
    return __builtin_amdgcn_perm(__float_as_uint(hi), __float_as_uint(lo), 0x07060302u);
}

// Monotone float -> uint mapping for atomicMax argmax keys.
__device__ __forceinline__ unsigned enc_f(float x) {
    unsigned u = __float_as_uint(x);
    return (u & 0x80000000u) ? ~u : (u | 0x80000000u);
}

// force value to SGPR
__device__ __forceinline__ float sgpr_f(float x) {
    return __uint_as_float(__builtin_amdgcn_readfirstlane(__float_as_uint(x)));
}

// Pre-swizzle W11/W12 into MFMA B-fragment order (bf16, RNE) + zero argBuf.
// B-layout for 16x16x32: B[k = KT*32 + (lane>>4)*8 + j][n = lane&15].
// BcWs (W12, 128 KB): [g(16)=wf*2+p2][lane(64)][t(8)=nn*4+KT][j(8)] -- each lane's
// 8 frags CONTIGUOUS (128 B): one base reg, ds-style imm offsets 0..112 (R8 lesson:
// computed per-frag addresses -> register pressure -> spills).
// BbWs (W11, 16 KB): [w(8)][KT(2)][lane(64)][j(8)].
__global__ void k_prep(const float* __restrict__ W11, const float* __restrict__ W12,
                       unsigned short* __restrict__ BbWs, unsigned short* __restrict__ BcWs,
                       unsigned long long* __restrict__ argBuf)
{
    int i = blockIdx.x * 256 + threadIdx.x;   // 65536 threads
    if (i < 8192) argBuf[i] = 0ull;
    {
        int j = i & 7, t = (i >> 3) & 7, l = (i >> 6) & 63, g = i >> 12;
        int wf = g >> 1, p2 = g & 1, nn = (t >> 2) & 1, KT = t & 3;
        int NT = p2 * 2 + nn;
        int k = KT * 32 + (l >> 4) * 8 + j;
        int f = wf * 64 + NT * 16 + (l & 15);
        BcWs[i] = f2bf(W12[(size_t)k * 512 + f]);
    }
    if (i < 8192) {
        int j = i & 7, l = (i >> 3) & 63, t = i >> 9;     // t = w*2 + KT
        int KT = t & 1, w = t >> 1;
        int k = KT * 32 + (l >> 4) * 8 + j;
        int f = w * 16 + (l & 15);
        BbWs[i] = f2bf(W11[(size_t)k * 128 + f]);
    }
}

// Shared mlp1 pipeline: 3->64->128->512 over nChunks x 128 points, per-feature
// argmax of PRE-ACTIVATION tracked in bestv[4] with 7-bit (ch,MT,r) code in the
// low mantissa (code = 127-(ch<<5|MT<<2|r): larger = earlier point).
// W12 B-frags STREAMED from L2 per chunk (2-NT blocking, 8 frags = 32 live regs)
// instead of 64 resident AGPRs -- frees the register wall that capped occupancy
// at 2 blocks/CU (R8 post-mortem). h0/h1 bf16-RTZ in padded LDS (R7 layout:
// immediate-offset ds_reads). xyz software-pipelined across stages B+C.
template<bool GATHER>
__device__ __forceinline__ void mlp1_pipeline(
    const float* __restrict__ cpts,                 // pts + c*nPts*3
    const unsigned long long* __restrict__ gIdx,    // argBuf + c*512 (GATHER only)
    int chunk0, int nChunks,
    const float* __restrict__ W10, const float* __restrict__ b10,
    const float* __restrict__ b11,
    const unsigned short* __restrict__ BbWs,
    const unsigned short* __restrict__ BcWs,
    unsigned short* __restrict__ s_h0,              // [128*72]
    unsigned short* __restrict__ s_h1,              // [128*136]
    int wf, int l, int lm, int q, float* bestv)
{
    // stage-A weights in SGPRs
    float wA0[8], wA1[8], wA2[8], bA[8];
    #pragma unroll
    for (int j = 0; j < 8; ++j) {
        wA0[j] = sgpr_f(W10[  0 + wf * 8 + j]);
        wA1[j] = sgpr_f(W10[ 64 + wf * 8 + j]);
        wA2[j] = sgpr_f(W10[128 + wf * 8 + j]);
        bA[j]  = sgpr_f(b10[       wf * 8 + j]);
    }

    // W11 B-frags resident (8 regs; small)
    short8 Bb0 = *(const short8*)(BbWs + (size_t)((wf * 2 + 0) * 64 + l) * 8);
    short8 Bb1 = *(const short8*)(BbWs + (size_t)((wf * 2 + 1) * 64 + l) * 8);

    const float bias11 = b11[wf * 16 + lm];
    const floatx4 bias4 = {bias11, bias11, bias11, bias11};
    const floatx4 fzero = {0.f, 0.f, 0.f, 0.f};

    #pragma unroll
    for (int NT = 0; NT < 4; ++NT) bestv[NT] = -INFINITY;

    // prefetch chunk0's two points (l and l+64)
    float ax[2], ay[2], az[2];
    {
        const int pb = chunk0 * 128;
        #pragma unroll
        for (int h = 0; h < 2; ++h) {
            const float* sp;
            if (GATHER) {
                unsigned gi = ~(unsigned)(gIdx[pb + h * 64 + l] & 0xFFFFFFFFull);
                sp = cpts + (size_t)gi * 3;
            } else {
                sp = cpts + (size_t)(pb + h * 64 + l) * 3;
            }
            ax[h] = sp[0]; ay[h] = sp[1]; az[h] = sp[2];
        }
    }

    for (int ch = 0; ch < nChunks; ++ch) {
        // ---- stage A: h0[128][64] = silu(pts @ W10 + b10) ----
        #pragma unroll
        for (int h = 0; h < 2; ++h) {
            float v[8];
            #pragma unroll
            for (int j = 0; j < 8; ++j) {
                float t = fmaf(az[h], wA2[j], bA[j]);
                t = fmaf(ay[h], wA1[j], t);
                t = fmaf(ax[h], wA0[j], t);
                v[j] = silu_f(t);
            }
            uint4 hv = { pk2bf_rtz(v[0], v[1]), pk2bf_rtz(v[2], v[3]),
                         pk2bf_rtz(v[4], v[5]), pk2bf_rtz(v[6], v[7]) };
            *(uint4*)&s_h0[(h * 64 + l) * 72 + wf * 8] = hv;   // 144B rows, 16B aligned
        }
        __syncthreads();   // orders stage C(ch-1) reads of s_h1 too

        // prefetch next chunk's points (in flight across stages B+C)
        if (ch + 1 < nChunks) {
            const int pb = (chunk0 + ch + 1) * 128;
            #pragma unroll
            for (int h = 0; h < 2; ++h) {
                const float* sp;
                if (GATHER) {
                    unsigned gi = ~(unsigned)(gIdx[pb + h * 64 + l] & 0xFFFFFFFFull);
                    sp = cpts + (size_t)gi * 3;
                } else {
                    sp = cpts + (size_t)(pb + h * 64 + l) * 3;
                }
                ax[h] = sp[0]; ay[h] = sp[1]; az[h] = sp[2];
            }
        }

        // ---- stage B: h1[128][128] = silu(h0 @ W11 + b11); bias4 as first-MFMA C ----
        #pragma unroll
        for (int MT = 0; MT < 8; ++MT) {
            const unsigned short* ar = s_h0 + (MT * 16 + lm) * 72;
            short8 a0 = *(const short8*)(ar + q * 8);
            short8 a1 = *(const short8*)(ar + 32 + q * 8);
            floatx4 acc = __builtin_amdgcn_mfma_f32_16x16x32_bf16(a0, Bb0, bias4, 0, 0, 0);
            acc = __builtin_amdgcn_mfma_f32_16x16x32_bf16(a1, Bb1, acc, 0, 0, 0);
            #pragma unroll
            for (int r = 0; r < 4; ++r) {   // C/D: row = q*4+r, col = lm
                unsigned uv = __float_as_uint(silu_f(acc[r]));   // RTZ b16 store
                s_h1[(MT * 16 + q * 4 + r) * 136 + wf * 16 + lm] = (unsigned short)(uv >> 16);
            }
        }
        __syncthreads();   // orders: stage B done -> h0 writable next chunk

        // ---- stage C: pre-act h1 @ W12; B streamed from L2, 2-NT blocking ----
        #pragma unroll
        for (int p2 = 0; p2 < 2; ++p2) {
            short8 Bn[8];   // 32 regs: frags for NT = p2*2 + {0,1}, KT 0..3
            {
                const unsigned short* bp = BcWs + (size_t)(((wf << 1) | p2) * 64 + l) * 64;
                #pragma unroll
                for (int t = 0; t < 8; ++t) Bn[t] = *(const short8*)(bp + t * 8);
            }
            #pragma unroll
            for (int MT = 0; MT < 8; ++MT) {
                const unsigned short* ar = s_h1 + (MT * 16 + lm) * 136;
                short8 a0 = *(const short8*)(ar + q * 8);
                short8 a1 = *(const short8*)(ar + 32 + q * 8);
                short8 a2 = *(const short8*)(ar + 64 + q * 8);
                short8 a3 = *(const short8*)(ar + 96 + q * 8);
                const int cbM = 127 - (ch << 5) - (MT << 2);
                #pragma unroll
                for (int nn = 0; nn < 2; ++nn) {
                    floatx4 acc = __builtin_amdgcn_mfma_f32_16x16x32_bf16(a0, Bn[nn * 4 + 0], fzero, 0, 0, 0);
                    acc = __builtin_amdgcn_mfma_f32_16x16x32_bf16(a1, Bn[nn * 4 + 1], acc, 0, 0, 0);
                    acc = __builtin_amdgcn_mfma_f32_16x16x32_bf16(a2, Bn[nn * 4 + 2], acc, 0, 0, 0);
                    acc = __builtin_amdgcn_mfma_f32_16x16x32_bf16(a3, Bn[nn * 4 + 3], acc, 0, 0, 0);
                    const int NT = p2 * 2 + nn;
                    float x0 = __uint_as_float((__float_as_uint(acc[0]) & 0xFFFFFF80u) | (unsigned)(cbM));
                    float x1 = __uint_as_float((__float_as_uint(acc[1]) & 0xFFFFFF80u) | (unsigned)(cbM - 1));
                    float x2 = __uint_as_float((__float_as_uint(acc[2]) & 0xFFFFFF80u) | (unsigned)(cbM - 2));
                    float x3 = __uint_as_float((__float_as_uint(acc[3]) & 0xFFFFFF80u) | (unsigned)(cbM - 3));
                    float t0 = fmaxf(fmaxf(x0, x1), x2);
                    bestv[NT] = fmaxf(fmaxf(t0, x3), bestv[NT]);
                }
            }
        }
    }
}

// Phase 1: big MLP + argmax over 65536 points/case.
// __launch_bounds__(512, 6): 85-reg budget -> 6 waves/SIMD -> 3 blocks/CU
// (LDS 52 KB x 3 = 156 KB fits). Watch for spill signature (WRITE_SIZE blowup).
__global__ __launch_bounds__(512, 6)
void k_mlp1_argmax(const float* __restrict__ pts,
                   const float* __restrict__ W10, const float* __restrict__ b10,
                   const float* __restrict__ b11, const float* __restrict__ b12,
                   const unsigned short* __restrict__ BbWs,
                   const unsigned short* __restrict__ BcWs,
                   unsigned long long* __restrict__ argOut)
{
    const int c = blockIdx.y, tid = threadIdx.x;
    const int wf = __builtin_amdgcn_readfirstlane(tid >> 6);
    const int l = tid & 63, lm = l & 15, q = l >> 4;

    __shared__ __align__(16) unsigned short s_h0[128 * 72];    // 18 KB
    __shared__ __align__(16) unsigned short s_h1[128 * 136];   // 34 KB

    float bestv[4];
    mlp1_pipeline<false>(pts + (size_t)c * NPTS_BIG * 3, nullptr,
                         blockIdx.x * 4, 4, W10, b10, b11, BbWs, BcWs,
                         s_h0, s_h1, wf, l, lm, q, bestv);

    // flush: decode code, strip it, combine quads via shfl, add b12, atomicMax
    #pragma unroll
    for (int NT = 0; NT < 4; ++NT) {
        unsigned u = __float_as_uint(bestv[NT]);
        int t = 127 - (int)(u & 127u);            // = ch<<5 | MT<<2 | r
        unsigned idx = (unsigned)((blockIdx.x * 4 + (t >> 5)) * 128
                                  + ((t >> 2) & 7) * 16 + q * 4 + (t & 3));
        float v = __uint_as_float(u & 0xFFFFFF80u) + b12[wf * 64 + NT * 16 + lm];
        #pragma unroll
        for (int m = 16; m <= 32; m <<= 1) {
            float    vo = __shfl_xor(v, m, 64);
            unsigned io = __shfl_xor(idx, m, 64);
            if (vo > v || (vo == v && io < idx)) { v = vo; idx = io; }
        }
        if (q == 0) {
            unsigned long long key = ((unsigned long long)enc_f(v) << 32)
                                   | (unsigned long long)(~idx);
            atomicMax(&argOut[(size_t)c * 512 + wf * 64 + NT * 16 + lm], key);
        }
    }
}

// Merged phase 2+3+4: one block per case. Gathers critical points via argBuf,
// runs mlp1 over 512 pts (4 chunks), max -> latent0 entirely in-block (no
// argBuf2, no atomics, no separate k_head launch), then head MLP inline.
__global__ __launch_bounds__(512)
void k_tail(const float* __restrict__ pts,
            const unsigned long long* __restrict__ argBuf,
            const float* __restrict__ W10, const float* __restrict__ b10,
            const float* __restrict__ b11, const float* __restrict__ b12,
            const unsigned short* __restrict__ BbWs,
            const unsigned short* __restrict__ BcWs,
            const float* __restrict__ W20, const float* __restrict__ b20,
            const float* __restrict__ W21, const float* __restrict__ b21,
            float* __restrict__ latent)
{
    const int c = blockIdx.x, tid = threadIdx.x;
    const int wf = __builtin_amdgcn_readfirstlane(tid >> 6);
    const int l = tid & 63, lm = l & 15, q = l >> 4;

    __shared__ __align__(16) unsigned short s_h0[128 * 72];
    __shared__ __align__(16) unsigned short s_h1[128 * 136];
    __shared__ float l0[512];
    __shared__ float red[512];
    __shared__ float hh[256];

    float bestv[4];
    mlp1_pipeline<true>(pts + (size_t)c * NPTS_BIG * 3, argBuf + (size_t)c * 512,
                        0, 4, W10, b10, b11, BbWs, BcWs,
                        s_h0, s_h1, wf, l, lm, q, bestv);

    // flush to LDS: strip tag, +b12, quad-max (values only), silu -> latent0
    #pragma unroll
    for (int NT = 0; NT < 4; ++NT) {
        float v = __uint_as_float(__float_as_uint(bestv[NT]) & 0xFFFFFF80u)
                + b12[wf * 64 + NT * 16 + lm];
        v = fmaxf(v, __shfl_xor(v, 16, 64));
        v = fmaxf(v, __shfl_xor(v, 32, 64));
        if (q == 0) l0[wf * 64 + NT * 16 + lm] = silu_f(v);
    }
    __syncthreads();

    // head layer 1: 512 -> 256, 2 k-slices x 256
    {
        const int f = tid & 255, s = tid >> 8;
        float acc = 0.f;
        #pragma unroll 8
        for (int k = s * 256; k < s * 256 + 256; ++k)
            acc = fmaf(l0[k], W20[(size_t)k * 256 + f], acc);
        red[s * 256 + f] = acc;
    }
    __syncthreads();
    if (tid < 256) hh[tid] = silu_f(red[tid] + red[256 + tid] + b20[tid]);
    __syncthreads();

    // head layer 2: 256 -> 512, one output per thread
    {
        float acc = 0.f;
        #pragma unroll 8
        for (int k = 0; k < 256; ++k)
            acc = fmaf(hh[k], W21[(size_t)k * 512 + tid], acc);
        latent[(size_t)c * 512 + tid] = acc + b21[tid];
    }
}

// out[b][:] = latent[x[b]][:]
__global__ void k_scatter(const int* __restrict__ x,
                          const float* __restrict__ latent,
                          float* __restrict__ out)
{
    const int b = blockIdx.x, t = threadIdx.x;   // 128 threads, float4 each
    int cid = x[b];
    const float4* src = (const float4*)(latent + (size_t)cid * 512);
    float4* dst = (float4*)(out + (size_t)b * 512);
    dst[t] = src[t];
}

extern "C" void kernel_launch(void* const* d_in, const int* in_sizes, int n_in,
                              void* d_out, int out_size, void* d_ws, size_t ws_size,
                              hipStream_t stream)
{
    const float* pts = (const float*)d_in[0];
    const float* W10 = (const float*)d_in[1];
    const float* b10 = (const float*)d_in[2];
    const float* W11 = (const float*)d_in[3];
    const float* b11 = (const float*)d_in[4];
    const float* W12 = (const float*)d_in[5];
    const float* b12 = (const float*)d_in[6];
    const float* W20 = (const float*)d_in[7];
    const float* b20 = (const float*)d_in[8];
    const float* W21 = (const float*)d_in[9];
    const float* b21 = (const float*)d_in[10];
    const int*   x   = (const int*)d_in[11];
    float* out = (float*)d_out;

    // Workspace layout (re-poisoned every call -> rebuild every call):
    char* ws = (char*)d_ws;
    unsigned long long* argBuf = (unsigned long long*)ws;            //  64 KB
    float* latent              = (float*)(ws + 65536);               //  32 KB
    unsigned short* BbWs       = (unsigned short*)(ws + 98304);      //  16 KB
    unsigned short* BcWs       = (unsigned short*)(ws + 114688);     // 128 KB (total 242 KB)

    // prep: swizzle weights to MFMA B-frag order + zero argBuf
    k_prep<<<dim3(256), dim3(256), 0, stream>>>(W11, W12, BbWs, BcWs, argBuf);

    // Phase 1: big MLP + argmax over 65536 points/case (128 blocks x 4 chunks x 128 pts)
    k_mlp1_argmax<<<dim3(128, NCASES), dim3(512), 0, stream>>>(
        pts, W10, b10, b11, b12, BbWs, BcWs, argBuf);

    // Phase 2+3+4 merged: gather + mlp1 over 512 critical pts + max + head, per case
    k_tail<<<dim3(NCASES), dim3(512), 0, stream>>>(
        pts, argBuf, W10, b10, b11, b12, BbWs, BcWs, W20, b20, W21, b21, latent);

    // Phase 5: scatter latent rows to output by case id
    k_scatter<<<dim3(OUT_B), dim3(128), 0, stream>>>(x, latent, out);
}

// Round 10
// 279.933 us; speedup vs baseline: 4.4760x; 4.4760x over previous
//
#include <hip/hip_runtime.h>
#include <math.h>

// Problem constants
#define NCASES   16
#define NPTS_BIG 65536
#define OUT_B    4096

typedef __attribute__((ext_vector_type(8))) short  short8;   // 8 bf16 = 4 VGPR (MFMA A/B frag)
typedef __attribute__((ext_vector_type(4))) float  floatx4;  // MFMA C/D frag

__device__ __forceinline__ float silu_f(float x) {
    return x * __builtin_amdgcn_rcpf(1.0f + __expf(-x));
}

// RNE fp32->bf16 (one-time prep only)
__device__ __forceinline__ unsigned f2bf_hi(float x) {
    unsigned u = __float_as_uint(x);
    return u + 0x7FFFu + ((u >> 16) & 1u);
}
__device__ __forceinline__ unsigned short f2bf(float x) {
    return (unsigned short)(f2bf_hi(x) >> 16);
}
// RTZ pack: two f32 -> two bf16 in one v_perm (hot loop)
__device__ __forceinline__ unsigned pk2bf_rtz(float lo, float hi) {
    return __builtin_amdgcn_perm(__float_as_uint(hi), __float_as_uint(lo), 0x07060302u);
}

// Monotone float -> uint mapping for atomicMax argmax keys.
__device__ __forceinline__ unsigned enc_f(float x) {
    unsigned u = __float_as_uint(x);
    return (u & 0x80000000u) ? ~u : (u | 0x80000000u);
}

// force value to SGPR
__device__ __forceinline__ float sgpr_f(float x) {
    return __uint_as_float(__builtin_amdgcn_readfirstlane(__float_as_uint(x)));
}

// Pre-swizzle W11/W12 into MFMA B-fragment order (bf16, RNE) + zero argBuf.
// B-layout for 16x16x32: B[k = KT*32 + (lane>>4)*8 + j][n = lane&15].
// BcWs: [w(8)][NT(4)][KT(4)][lane(64)][j(8)]  (W12, 128 KB)  -- R7 layout
// BbWs: [w(8)][KT(2)][lane(64)][j(8)]         (W11, 16 KB)
__global__ void k_prep(const float* __restrict__ W11, const float* __restrict__ W12,
                       unsigned short* __restrict__ BbWs, unsigned short* __restrict__ BcWs,
                       unsigned long long* __restrict__ argBuf)
{
    int i = blockIdx.x * 256 + threadIdx.x;   // 65536 threads
    if (i < 8192) argBuf[i] = 0ull;
    {
        int j = i & 7, l = (i >> 3) & 63, t = i >> 9;     // t = w*16 + NT*4 + KT
        int KT = t & 3, NT = (t >> 2) & 3, w = t >> 4;
        int k = KT * 32 + (l >> 4) * 8 + j;
        int f = w * 64 + NT * 16 + (l & 15);
        BcWs[i] = f2bf(W12[(size_t)k * 512 + f]);
    }
    if (i < 8192) {
        int j = i & 7, l = (i >> 3) & 63, t = i >> 9;     // t = w*2 + KT
        int KT = t & 1, w = t >> 1;
        int k = KT * 32 + (l >> 4) * 8 + j;
        int f = w * 16 + (l & 15);
        BbWs[i] = f2bf(W11[(size_t)k * 128 + f]);
    }
}

// Shared mlp1 pipeline (R7-proven config): 3->64->128->512 over nChunks x 128 pts,
// per-feature argmax of PRE-ACTIVATION in bestv[4], 7-bit (ch,MT,r) code in low
// mantissa (code = 127-(ch<<5|MT<<2|r): larger = earlier point, first-occurrence).
// Bc RESIDENT in 64 AGPRs (R8/R9 lesson: streaming/swizzle alternatives spill --
// the viable point is 64A + <=64V at 4 waves/SIMD). h0/h1 bf16-RTZ in padded LDS
// (144B/272B rows: immediate-offset ds_reads). xyz software-pipelined across B+C.
template<bool GATHER>
__device__ __forceinline__ void mlp1_pipeline(
    const float* __restrict__ cpts,                 // pts + c*nPts*3
    const unsigned long long* __restrict__ gIdx,    // argBuf + c*512 (GATHER only)
    int chunk0, int nChunks,
    const float* __restrict__ W10, const float* __restrict__ b10,
    const float* __restrict__ b11,
    const unsigned short* __restrict__ BbWs,
    const unsigned short* __restrict__ BcWs,
    unsigned short* __restrict__ s_h0,              // [128*72]
    unsigned short* __restrict__ s_h1,              // [128*136]
    int wf, int l, int lm, int q, float* bestv)
{
    // stage-A weights in SGPRs
    float wA0[8], wA1[8], wA2[8], bA[8];
    #pragma unroll
    for (int j = 0; j < 8; ++j) {
        wA0[j] = sgpr_f(W10[  0 + wf * 8 + j]);
        wA1[j] = sgpr_f(W10[ 64 + wf * 8 + j]);
        wA2[j] = sgpr_f(W10[128 + wf * 8 + j]);
        bA[j]  = sgpr_f(b10[       wf * 8 + j]);
    }

    // persistent B fragments (AGPR side of the unified file)
    short8 Bc[16];   // [NT*4+KT] for W12 slice: 64 AGPRs
    #pragma unroll
    for (int t = 0; t < 16; ++t)
        Bc[t] = *(const short8*)(BcWs + (size_t)((wf * 16 + t) * 64 + l) * 8);
    short8 Bb0 = *(const short8*)(BbWs + (size_t)((wf * 2 + 0) * 64 + l) * 8);
    short8 Bb1 = *(const short8*)(BbWs + (size_t)((wf * 2 + 1) * 64 + l) * 8);

    const float bias11 = b11[wf * 16 + lm];
    const floatx4 bias4 = {bias11, bias11, bias11, bias11};
    const floatx4 fzero = {0.f, 0.f, 0.f, 0.f};

    #pragma unroll
    for (int NT = 0; NT < 4; ++NT) bestv[NT] = -INFINITY;

    // prefetch chunk0's two points (l and l+64)
    float ax[2], ay[2], az[2];
    {
        const int pb = chunk0 * 128;
        #pragma unroll
        for (int h = 0; h < 2; ++h) {
            const float* sp;
            if (GATHER) {
                unsigned gi = ~(unsigned)(gIdx[pb + h * 64 + l] & 0xFFFFFFFFull);
                sp = cpts + (size_t)gi * 3;
            } else {
                sp = cpts + (size_t)(pb + h * 64 + l) * 3;
            }
            ax[h] = sp[0]; ay[h] = sp[1]; az[h] = sp[2];
        }
    }

    for (int ch = 0; ch < nChunks; ++ch) {
        // ---- stage A: h0[128][64] = silu(pts @ W10 + b10) ----
        #pragma unroll
        for (int h = 0; h < 2; ++h) {
            float v[8];
            #pragma unroll
            for (int j = 0; j < 8; ++j) {
                float t = fmaf(az[h], wA2[j], bA[j]);
                t = fmaf(ay[h], wA1[j], t);
                t = fmaf(ax[h], wA0[j], t);
                v[j] = silu_f(t);
            }
            uint4 hv = { pk2bf_rtz(v[0], v[1]), pk2bf_rtz(v[2], v[3]),
                         pk2bf_rtz(v[4], v[5]), pk2bf_rtz(v[6], v[7]) };
            *(uint4*)&s_h0[(h * 64 + l) * 72 + wf * 8] = hv;   // 144B rows, 16B aligned
        }
        __syncthreads();   // orders stage C(ch-1) reads of s_h1 too

        // prefetch next chunk's points (in flight across stages B+C)
        if (ch + 1 < nChunks) {
            const int pb = (chunk0 + ch + 1) * 128;
            #pragma unroll
            for (int h = 0; h < 2; ++h) {
                const float* sp;
                if (GATHER) {
                    unsigned gi = ~(unsigned)(gIdx[pb + h * 64 + l] & 0xFFFFFFFFull);
                    sp = cpts + (size_t)gi * 3;
                } else {
                    sp = cpts + (size_t)(pb + h * 64 + l) * 3;
                }
                ax[h] = sp[0]; ay[h] = sp[1]; az[h] = sp[2];
            }
        }

        // ---- stage B: h1[128][128] = silu(h0 @ W11 + b11); bias4 as first-MFMA C ----
        #pragma unroll
        for (int MT = 0; MT < 8; ++MT) {
            const unsigned short* ar = s_h0 + (MT * 16 + lm) * 72;
            short8 a0 = *(const short8*)(ar + q * 8);
            short8 a1 = *(const short8*)(ar + 32 + q * 8);
            floatx4 acc = __builtin_amdgcn_mfma_f32_16x16x32_bf16(a0, Bb0, bias4, 0, 0, 0);
            acc = __builtin_amdgcn_mfma_f32_16x16x32_bf16(a1, Bb1, acc, 0, 0, 0);
            #pragma unroll
            for (int r = 0; r < 4; ++r) {   // C/D: row = q*4+r, col = lm
                unsigned uv = __float_as_uint(silu_f(acc[r]));   // RTZ b16 store
                s_h1[(MT * 16 + q * 4 + r) * 136 + wf * 16 + lm] = (unsigned short)(uv >> 16);
            }
        }
        __syncthreads();   // orders: stage B done -> h0 writable next chunk

        // ---- stage C: pre-act h1 @ W12; code-in-mantissa max argmax ----
        #pragma unroll
        for (int MT = 0; MT < 8; ++MT) {
            const unsigned short* ar = s_h1 + (MT * 16 + lm) * 136;
            short8 a[4];
            #pragma unroll
            for (int KT = 0; KT < 4; ++KT)
                a[KT] = *(const short8*)(ar + KT * 32 + q * 8);
            const int cbM = 127 - (ch << 5) - (MT << 2);
            #pragma unroll
            for (int NT = 0; NT < 4; ++NT) {
                floatx4 acc = __builtin_amdgcn_mfma_f32_16x16x32_bf16(a[0], Bc[NT * 4], fzero, 0, 0, 0);
                #pragma unroll
                for (int KT = 1; KT < 4; ++KT)
                    acc = __builtin_amdgcn_mfma_f32_16x16x32_bf16(a[KT], Bc[NT * 4 + KT], acc, 0, 0, 0);
                // (bits & ~127) | code -> v_and_or_b32; decode exact at flush
                float x0 = __uint_as_float((__float_as_uint(acc[0]) & 0xFFFFFF80u) | (unsigned)(cbM));
                float x1 = __uint_as_float((__float_as_uint(acc[1]) & 0xFFFFFF80u) | (unsigned)(cbM - 1));
                float x2 = __uint_as_float((__float_as_uint(acc[2]) & 0xFFFFFF80u) | (unsigned)(cbM - 2));
                float x3 = __uint_as_float((__float_as_uint(acc[3]) & 0xFFFFFF80u) | (unsigned)(cbM - 3));
                float t0 = fmaxf(fmaxf(x0, x1), x2);
                bestv[NT] = fmaxf(fmaxf(t0, x3), bestv[NT]);
            }
        }
    }
}

// Phase 1: big MLP + argmax over 65536 points/case. R7-proven config:
// __launch_bounds__(512,4), 64 AGPR Bc + 64 VGPR, 53.25 KB LDS, 2 blocks/CU.
__global__ __launch_bounds__(512, 4)
void k_mlp1_argmax(const float* __restrict__ pts,
                   const float* __restrict__ W10, const float* __restrict__ b10,
                   const float* __restrict__ b11, const float* __restrict__ b12,
                   const unsigned short* __restrict__ BbWs,
                   const unsigned short* __restrict__ BcWs,
                   unsigned long long* __restrict__ argOut)
{
    const int c = blockIdx.y, tid = threadIdx.x;
    const int wf = __builtin_amdgcn_readfirstlane(tid >> 6);
    const int l = tid & 63, lm = l & 15, q = l >> 4;

    __shared__ __align__(16) unsigned short s_h0[128 * 72];    // 18 KB
    __shared__ __align__(16) unsigned short s_h1[128 * 136];   // 34 KB

    float bestv[4];
    mlp1_pipeline<false>(pts + (size_t)c * NPTS_BIG * 3, nullptr,
                         blockIdx.x * 4, 4, W10, b10, b11, BbWs, BcWs,
                         s_h0, s_h1, wf, l, lm, q, bestv);

    // flush: decode code, strip it, combine quads via shfl, add b12, atomicMax
    #pragma unroll
    for (int NT = 0; NT < 4; ++NT) {
        unsigned u = __float_as_uint(bestv[NT]);
        int t = 127 - (int)(u & 127u);            // = ch<<5 | MT<<2 | r (exact)
        unsigned idx = (unsigned)((blockIdx.x * 4 + (t >> 5)) * 128
                                  + ((t >> 2) & 7) * 16 + q * 4 + (t & 3));
        float v = __uint_as_float(u & 0xFFFFFF80u) + b12[wf * 64 + NT * 16 + lm];
        #pragma unroll
        for (int m = 16; m <= 32; m <<= 1) {
            float    vo = __shfl_xor(v, m, 64);
            unsigned io = __shfl_xor(idx, m, 64);
            if (vo > v || (vo == v && io < idx)) { v = vo; idx = io; }
        }
        if (q == 0) {
            unsigned long long key = ((unsigned long long)enc_f(v) << 32)
                                   | (unsigned long long)(~idx);
            atomicMax(&argOut[(size_t)c * 512 + wf * 64 + NT * 16 + lm], key);
        }
    }
}

// Merged phase 2+3+4: one block per case. Gathers critical points via argBuf,
// runs mlp1 over 512 pts (4 chunks), in-block max -> latent0 (no argBuf2, no
// atomics, no separate launches), then head MLP inline.
__global__ __launch_bounds__(512, 4)
void k_tail(const float* __restrict__ pts,
            const unsigned long long* __restrict__ argBuf,
            const float* __restrict__ W10, const float* __restrict__ b10,
            const float* __restrict__ b11, const float* __restrict__ b12,
            const unsigned short* __restrict__ BbWs,
            const unsigned short* __restrict__ BcWs,
            const float* __restrict__ W20, const float* __restrict__ b20,
            const float* __restrict__ W21, const float* __restrict__ b21,
            float* __restrict__ latent)
{
    const int c = blockIdx.x, tid = threadIdx.x;
    const int wf = __builtin_amdgcn_readfirstlane(tid >> 6);
    const int l = tid & 63, lm = l & 15, q = l >> 4;

    __shared__ __align__(16) unsigned short s_h0[128 * 72];
    __shared__ __align__(16) unsigned short s_h1[128 * 136];
    __shared__ float l0[512];
    __shared__ float red[512];
    __shared__ float hh[256];

    float bestv[4];
    mlp1_pipeline<true>(pts + (size_t)c * NPTS_BIG * 3, argBuf + (size_t)c * 512,
                        0, 4, W10, b10, b11, BbWs, BcWs,
                        s_h0, s_h1, wf, l, lm, q, bestv);

    // flush to LDS: strip tag, +b12, quad-max (values only), silu -> latent0
    #pragma unroll
    for (int NT = 0; NT < 4; ++NT) {
        float v = __uint_as_float(__float_as_uint(bestv[NT]) & 0xFFFFFF80u)
                + b12[wf * 64 + NT * 16 + lm];
        v = fmaxf(v, __shfl_xor(v, 16, 64));
        v = fmaxf(v, __shfl_xor(v, 32, 64));
        if (q == 0) l0[wf * 64 + NT * 16 + lm] = silu_f(v);
    }
    __syncthreads();

    // head layer 1: 512 -> 256, 2 k-slices x 256
    {
        const int f = tid & 255, s = tid >> 8;
        float acc = 0.f;
        #pragma unroll 8
        for (int k = s * 256; k < s * 256 + 256; ++k)
            acc = fmaf(l0[k], W20[(size_t)k * 256 + f], acc);
        red[s * 256 + f] = acc;
    }
    __syncthreads();
    if (tid < 256) hh[tid] = silu_f(red[tid] + red[256 + tid] + b20[tid]);
    __syncthreads();

    // head layer 2: 256 -> 512, one output per thread
    {
        float acc = 0.f;
        #pragma unroll 8
        for (int k = 0; k < 256; ++k)
            acc = fmaf(hh[k], W21[(size_t)k * 512 + tid], acc);
        latent[(size_t)c * 512 + tid] = acc + b21[tid];
    }
}

// out[b][:] = latent[x[b]][:]
__global__ void k_scatter(const int* __restrict__ x,
                          const float* __restrict__ latent,
                          float* __restrict__ out)
{
    const int b = blockIdx.x, t = threadIdx.x;   // 128 threads, float4 each
    int cid = x[b];
    const float4* src = (const float4*)(latent + (size_t)cid * 512);
    float4* dst = (float4*)(out + (size_t)b * 512);
    dst[t] = src[t];
}

extern "C" void kernel_launch(void* const* d_in, const int* in_sizes, int n_in,
                              void* d_out, int out_size, void* d_ws, size_t ws_size,
                              hipStream_t stream)
{
    const float* pts = (const float*)d_in[0];
    const float* W10 = (const float*)d_in[1];
    const float* b10 = (const float*)d_in[2];
    const float* W11 = (const float*)d_in[3];
    const float* b11 = (const float*)d_in[4];
    const float* W12 = (const float*)d_in[5];
    const float* b12 = (const float*)d_in[6];
    const float* W20 = (const float*)d_in[7];
    const float* b20 = (const float*)d_in[8];
    const float* W21 = (const float*)d_in[9];
    const float* b21 = (const float*)d_in[10];
    const int*   x   = (const int*)d_in[11];
    float* out = (float*)d_out;

    // Workspace layout (re-poisoned every call -> rebuild every call):
    char* ws = (char*)d_ws;
    unsigned long long* argBuf = (unsigned long long*)ws;            //  64 KB
    float* latent              = (float*)(ws + 65536);               //  32 KB
    unsigned short* BbWs       = (unsigned short*)(ws + 98304);      //  16 KB
    unsigned short* BcWs       = (unsigned short*)(ws + 114688);     // 128 KB (total 242 KB)

    // prep: swizzle weights to MFMA B-frag order + zero argBuf
    k_prep<<<dim3(256), dim3(256), 0, stream>>>(W11, W12, BbWs, BcWs, argBuf);

    // Phase 1: big MLP + argmax over 65536 points/case (128 blocks x 4 chunks x 128 pts)
    k_mlp1_argmax<<<dim3(128, NCASES), dim3(512), 0, stream>>>(
        pts, W10, b10, b11, b12, BbWs, BcWs, argBuf);

    // Phase 2+3+4 merged: gather + mlp1 over 512 critical pts + max + head, per case
    k_tail<<<dim3(NCASES), dim3(512), 0, stream>>>(
        pts, argBuf, W10, b10, b11, b12, BbWs, BcWs, W20, b20, W21, b21, latent);

    // Phase 5: scatter latent rows to output by case id
    k_scatter<<<dim3(OUT_B), dim3(128), 0, stream>>>(x, latent, out);
}

// Round 11
// 269.076 us; speedup vs baseline: 4.6566x; 1.0403x over previous
//
#include <hip/hip_runtime.h>
#include <math.h>

// Problem constants
#define NCASES   16
#define NPTS_BIG 65536
#define OUT_B    4096

typedef __attribute__((ext_vector_type(8))) short  short8;   // 8 bf16 = 4 VGPR (MFMA A/B frag)
typedef __attribute__((ext_vector_type(4))) float  floatx4;  // MFMA C/D frag

__device__ __forceinline__ float silu_f(float x) {
    return x * __builtin_amdgcn_rcpf(1.0f + __expf(-x));
}

// RNE fp32->bf16 (one-time prep only)
__device__ __forceinline__ unsigned f2bf_hi(float x) {
    unsigned u = __float_as_uint(x);
    return u + 0x7FFFu + ((u >> 16) & 1u);
}
__device__ __forceinline__ unsigned short f2bf(float x) {
    return (unsigned short)(f2bf_hi(x) >> 16);
}
// RTZ pack: two f32 -> two bf16 in one v_perm (hot loop)
__device__ __forceinline__ unsigned pk2bf_rtz(float lo, float hi) {
    return __builtin_amdgcn_perm(__float_as_uint(hi), __float_as_uint(lo), 0x07060302u);
}

// Monotone float -> uint mapping for atomicMax argmax keys.
__device__ __forceinline__ unsigned enc_f(float x) {
    unsigned u = __float_as_uint(x);
    return (u & 0x80000000u) ? ~u : (u | 0x80000000u);
}

// force value to SGPR
__device__ __forceinline__ float sgpr_f(float x) {
    return __uint_as_float(__builtin_amdgcn_readfirstlane(__float_as_uint(x)));
}

// Pre-swizzle W11/W12 into MFMA B-fragment order (bf16, RNE) + zero argBuf.
// B-layout for 16x16x32: B[k = KT*32 + (lane>>4)*8 + j][n = lane&15].
// BcWs: [w(8)][NT(4)][KT(4)][lane(64)][j(8)]  (W12, 128 KB)
// BbWs: [w(8)][KT(2)][lane(64)][j(8)]         (W11, 16 KB)
__global__ void k_prep(const float* __restrict__ W11, const float* __restrict__ W12,
                       unsigned short* __restrict__ BbWs, unsigned short* __restrict__ BcWs,
                       unsigned long long* __restrict__ argBuf)
{
    int i = blockIdx.x * 256 + threadIdx.x;   // 65536 threads
    if (i < 8192) argBuf[i] = 0ull;
    {
        int j = i & 7, l = (i >> 3) & 63, t = i >> 9;     // t = w*16 + NT*4 + KT
        int KT = t & 3, NT = (t >> 2) & 3, w = t >> 4;
        int k = KT * 32 + (l >> 4) * 8 + j;
        int f = w * 64 + NT * 16 + (l & 15);
        BcWs[i] = f2bf(W12[(size_t)k * 512 + f]);
    }
    if (i < 8192) {
        int j = i & 7, l = (i >> 3) & 63, t = i >> 9;     // t = w*2 + KT
        int KT = t & 1, w = t >> 1;
        int k = KT * 32 + (l >> 4) * 8 + j;
        int f = w * 16 + (l & 15);
        BbWs[i] = f2bf(W11[(size_t)k * 128 + f]);
    }
}

// Shared mlp1 pipeline (R7/R10-proven config): 3->64->128->512 over nChunks x 128
// pts, per-feature argmax of PRE-ACTIVATION in bestv[4], 7-bit (ch,MT,r) code in
// low mantissa (code = 127-(ch<<5|MT<<2|r): larger = earlier, first-occurrence).
// Bc RESIDENT in 64 AGPRs (R8/R9 lesson: streaming/swizzle alternatives spill --
// viable point is 64A + <=64V at 4 waves/SIMD). h0/h1 bf16-RTZ in padded LDS
// (144B/272B rows: immediate-offset ds_reads). xyz software-pipelined across B+C.
template<bool GATHER>
__device__ __forceinline__ void mlp1_pipeline(
    const float* __restrict__ cpts,
    const unsigned long long* __restrict__ gIdx,
    int chunk0, int nChunks,
    const float* __restrict__ W10, const float* __restrict__ b10,
    const float* __restrict__ b11,
    const unsigned short* __restrict__ BbWs,
    const unsigned short* __restrict__ BcWs,
    unsigned short* __restrict__ s_h0,              // [128*72]
    unsigned short* __restrict__ s_h1,              // [128*136]
    int wf, int l, int lm, int q, float* bestv)
{
    // stage-A weights in SGPRs
    float wA0[8], wA1[8], wA2[8], bA[8];
    #pragma unroll
    for (int j = 0; j < 8; ++j) {
        wA0[j] = sgpr_f(W10[  0 + wf * 8 + j]);
        wA1[j] = sgpr_f(W10[ 64 + wf * 8 + j]);
        wA2[j] = sgpr_f(W10[128 + wf * 8 + j]);
        bA[j]  = sgpr_f(b10[       wf * 8 + j]);
    }

    // persistent B fragments (AGPR side of the unified file)
    short8 Bc[16];
    #pragma unroll
    for (int t = 0; t < 16; ++t)
        Bc[t] = *(const short8*)(BcWs + (size_t)((wf * 16 + t) * 64 + l) * 8);
    short8 Bb0 = *(const short8*)(BbWs + (size_t)((wf * 2 + 0) * 64 + l) * 8);
    short8 Bb1 = *(const short8*)(BbWs + (size_t)((wf * 2 + 1) * 64 + l) * 8);

    const float bias11 = b11[wf * 16 + lm];
    const floatx4 bias4 = {bias11, bias11, bias11, bias11};
    const floatx4 fzero = {0.f, 0.f, 0.f, 0.f};

    #pragma unroll
    for (int NT = 0; NT < 4; ++NT) bestv[NT] = -INFINITY;

    // prefetch chunk0's two points (l and l+64)
    float ax[2], ay[2], az[2];
    {
        const int pb = chunk0 * 128;
        #pragma unroll
        for (int h = 0; h < 2; ++h) {
            const float* sp;
            if (GATHER) {
                unsigned gi = ~(unsigned)(gIdx[pb + h * 64 + l] & 0xFFFFFFFFull);
                sp = cpts + (size_t)gi * 3;
            } else {
                sp = cpts + (size_t)(pb + h * 64 + l) * 3;
            }
            ax[h] = sp[0]; ay[h] = sp[1]; az[h] = sp[2];
        }
    }

    for (int ch = 0; ch < nChunks; ++ch) {
        // ---- stage A: h0[128][64] = silu(pts @ W10 + b10) ----
        #pragma unroll
        for (int h = 0; h < 2; ++h) {
            float v[8];
            #pragma unroll
            for (int j = 0; j < 8; ++j) {
                float t = fmaf(az[h], wA2[j], bA[j]);
                t = fmaf(ay[h], wA1[j], t);
                t = fmaf(ax[h], wA0[j], t);
                v[j] = silu_f(t);
            }
            uint4 hv = { pk2bf_rtz(v[0], v[1]), pk2bf_rtz(v[2], v[3]),
                         pk2bf_rtz(v[4], v[5]), pk2bf_rtz(v[6], v[7]) };
            *(uint4*)&s_h0[(h * 64 + l) * 72 + wf * 8] = hv;
        }
        __syncthreads();

        // prefetch next chunk's points (in flight across stages B+C)
        if (ch + 1 < nChunks) {
            const int pb = (chunk0 + ch + 1) * 128;
            #pragma unroll
            for (int h = 0; h < 2; ++h) {
                const float* sp;
                if (GATHER) {
                    unsigned gi = ~(unsigned)(gIdx[pb + h * 64 + l] & 0xFFFFFFFFull);
                    sp = cpts + (size_t)gi * 3;
                } else {
                    sp = cpts + (size_t)(pb + h * 64 + l) * 3;
                }
                ax[h] = sp[0]; ay[h] = sp[1]; az[h] = sp[2];
            }
        }

        // ---- stage B: h1[128][128] = silu(h0 @ W11 + b11) ----
        #pragma unroll
        for (int MT = 0; MT < 8; ++MT) {
            const unsigned short* ar = s_h0 + (MT * 16 + lm) * 72;
            short8 a0 = *(const short8*)(ar + q * 8);
            short8 a1 = *(const short8*)(ar + 32 + q * 8);
            floatx4 acc = __builtin_amdgcn_mfma_f32_16x16x32_bf16(a0, Bb0, bias4, 0, 0, 0);
            acc = __builtin_amdgcn_mfma_f32_16x16x32_bf16(a1, Bb1, acc, 0, 0, 0);
            #pragma unroll
            for (int r = 0; r < 4; ++r) {
                unsigned uv = __float_as_uint(silu_f(acc[r]));   // RTZ b16 store
                s_h1[(MT * 16 + q * 4 + r) * 136 + wf * 16 + lm] = (unsigned short)(uv >> 16);
            }
        }
        __syncthreads();

        // ---- stage C: pre-act h1 @ W12; code-in-mantissa max argmax ----
        #pragma unroll
        for (int MT = 0; MT < 8; ++MT) {
            const unsigned short* ar = s_h1 + (MT * 16 + lm) * 136;
            short8 a[4];
            #pragma unroll
            for (int KT = 0; KT < 4; ++KT)
                a[KT] = *(const short8*)(ar + KT * 32 + q * 8);
            const int cbM = 127 - (ch << 5) - (MT << 2);
            #pragma unroll
            for (int NT = 0; NT < 4; ++NT) {
                floatx4 acc = __builtin_amdgcn_mfma_f32_16x16x32_bf16(a[0], Bc[NT * 4], fzero, 0, 0, 0);
                #pragma unroll
                for (int KT = 1; KT < 4; ++KT)
                    acc = __builtin_amdgcn_mfma_f32_16x16x32_bf16(a[KT], Bc[NT * 4 + KT], acc, 0, 0, 0);
                float x0 = __uint_as_float((__float_as_uint(acc[0]) & 0xFFFFFF80u) | (unsigned)(cbM));
                float x1 = __uint_as_float((__float_as_uint(acc[1]) & 0xFFFFFF80u) | (unsigned)(cbM - 1));
                float x2 = __uint_as_float((__float_as_uint(acc[2]) & 0xFFFFFF80u) | (unsigned)(cbM - 2));
                float x3 = __uint_as_float((__float_as_uint(acc[3]) & 0xFFFFFF80u) | (unsigned)(cbM - 3));
                float t0 = fmaxf(fmaxf(x0, x1), x2);
                bestv[NT] = fmaxf(fmaxf(t0, x3), bestv[NT]);
            }
        }
    }
}

// Phase 1: big MLP + argmax over 65536 points/case. R10-proven, unchanged.
__global__ __launch_bounds__(512, 4)
void k_mlp1_argmax(const float* __restrict__ pts,
                   const float* __restrict__ W10, const float* __restrict__ b10,
                   const float* __restrict__ b11, const float* __restrict__ b12,
                   const unsigned short* __restrict__ BbWs,
                   const unsigned short* __restrict__ BcWs,
                   unsigned long long* __restrict__ argOut)
{
    const int c = blockIdx.y, tid = threadIdx.x;
    const int wf = __builtin_amdgcn_readfirstlane(tid >> 6);
    const int l = tid & 63, lm = l & 15, q = l >> 4;

    __shared__ __align__(16) unsigned short s_h0[128 * 72];    // 18 KB
    __shared__ __align__(16) unsigned short s_h1[128 * 136];   // 34 KB

    float bestv[4];
    mlp1_pipeline<false>(pts + (size_t)c * NPTS_BIG * 3, nullptr,
                         blockIdx.x * 4, 4, W10, b10, b11, BbWs, BcWs,
                         s_h0, s_h1, wf, l, lm, q, bestv);

    #pragma unroll
    for (int NT = 0; NT < 4; ++NT) {
        unsigned u = __float_as_uint(bestv[NT]);
        int t = 127 - (int)(u & 127u);            // = ch<<5 | MT<<2 | r (exact)
        unsigned idx = (unsigned)((blockIdx.x * 4 + (t >> 5)) * 128
                                  + ((t >> 2) & 7) * 16 + q * 4 + (t & 3));
        float v = __uint_as_float(u & 0xFFFFFF80u) + b12[wf * 64 + NT * 16 + lm];
        #pragma unroll
        for (int m = 16; m <= 32; m <<= 1) {
            float    vo = __shfl_xor(v, m, 64);
            unsigned io = __shfl_xor(idx, m, 64);
            if (vo > v || (vo == v && io < idx)) { v = vo; idx = io; }
        }
        if (q == 0) {
            unsigned long long key = ((unsigned long long)enc_f(v) << 32)
                                   | (unsigned long long)(~idx);
            atomicMax(&argOut[(size_t)c * 512 + wf * 64 + NT * 16 + lm], key);
        }
    }
}

// Mega-tail: one block per case. Gather critical points via argBuf, mlp1 over
// 512 pts, in-block max -> latent0, head MLP (4-acc unroll: 32 loads in flight
// per burst -- R10 lesson: serial unroll-8 chains left head HBM-latency-bound at
// ~12 us/layer cold), then scatter rows of `out` directly via per-wave ballot scan
// of x (kills the k_scatter launch + latent round-trip).
__global__ __launch_bounds__(512, 4)
void k_tail(const float* __restrict__ pts,
            const unsigned long long* __restrict__ argBuf,
            const float* __restrict__ W10, const float* __restrict__ b10,
            const float* __restrict__ b11, const float* __restrict__ b12,
            const unsigned short* __restrict__ BbWs,
            const unsigned short* __restrict__ BcWs,
            const float* __restrict__ W20, const float* __restrict__ b20,
            const float* __restrict__ W21, const float* __restrict__ b21,
            const int* __restrict__ x, float* __restrict__ out)
{
    const int c = blockIdx.x, tid = threadIdx.x;
    const int wf = __builtin_amdgcn_readfirstlane(tid >> 6);
    const int l = tid & 63, lm = l & 15, q = l >> 4;

    __shared__ __align__(16) unsigned short s_h0[128 * 72];
    __shared__ __align__(16) unsigned short s_h1[128 * 136];
    __shared__ float l0[512];
    __shared__ float red[512];
    __shared__ float hh[256];

    float bestv[4];
    mlp1_pipeline<true>(pts + (size_t)c * NPTS_BIG * 3, argBuf + (size_t)c * 512,
                        0, 4, W10, b10, b11, BbWs, BcWs,
                        s_h0, s_h1, wf, l, lm, q, bestv);

    // flush to LDS: strip tag, +b12, quad-max (values only), silu -> latent0
    #pragma unroll
    for (int NT = 0; NT < 4; ++NT) {
        float v = __uint_as_float(__float_as_uint(bestv[NT]) & 0xFFFFFF80u)
                + b12[wf * 64 + NT * 16 + lm];
        v = fmaxf(v, __shfl_xor(v, 16, 64));
        v = fmaxf(v, __shfl_xor(v, 32, 64));
        if (q == 0) l0[wf * 64 + NT * 16 + lm] = silu_f(v);
    }
    __syncthreads();

    // head layer 1: 512 -> 256; 2 k-slices x 256; 4 independent accumulators
    {
        const int f = tid & 255, s = tid >> 8;
        const float* Wp = W20 + (size_t)(s * 256) * 256 + f;
        const float* lp = l0 + s * 256;
        float a0 = 0.f, a1 = 0.f, a2 = 0.f, a3 = 0.f;
        #pragma unroll 8
        for (int k = 0; k < 256; k += 4) {
            a0 = fmaf(lp[k],     Wp[(size_t)k * 256],       a0);
            a1 = fmaf(lp[k + 1], Wp[(size_t)(k + 1) * 256], a1);
            a2 = fmaf(lp[k + 2], Wp[(size_t)(k + 2) * 256], a2);
            a3 = fmaf(lp[k + 3], Wp[(size_t)(k + 3) * 256], a3);
        }
        red[s * 256 + f] = (a0 + a1) + (a2 + a3);
    }
    __syncthreads();
    if (tid < 256) hh[tid] = silu_f(red[tid] + red[256 + tid] + b20[tid]);
    __syncthreads();

    // head layer 2: 256 -> 512; one output per thread; 4 accumulators
    {
        const float* Wp = W21 + tid;
        float a0 = 0.f, a1 = 0.f, a2 = 0.f, a3 = 0.f;
        #pragma unroll 8
        for (int k = 0; k < 256; k += 4) {
            a0 = fmaf(hh[k],     Wp[(size_t)k * 512],       a0);
            a1 = fmaf(hh[k + 1], Wp[(size_t)(k + 1) * 512], a1);
            a2 = fmaf(hh[k + 2], Wp[(size_t)(k + 2) * 512], a2);
            a3 = fmaf(hh[k + 3], Wp[(size_t)(k + 3) * 512], a3);
        }
        red[tid] = (a0 + a1) + (a2 + a3) + b21[tid];   // final latent row
    }
    __syncthreads();

    // fused scatter: wave wf scans b in [wf*512, wf*512+512); for each b with
    // x[b]==c the whole wave writes out[b][:] (lane l owns floats [8l, 8l+8)).
    {
        float4 r0 = *(float4*)&red[l * 8];
        float4 r1 = *(float4*)&red[l * 8 + 4];
        #pragma unroll 1
        for (int i = 0; i < 8; ++i) {
            const int b = wf * 512 + i * 64 + l;
            unsigned long long mask = __ballot(x[b] == c);
            while (mask) {
                int s = __ffsll((long long)mask) - 1;
                mask &= mask - 1;
                const int bb = wf * 512 + i * 64 + s;
                float4* dst = (float4*)(out + (size_t)bb * 512 + l * 8);
                dst[0] = r0; dst[1] = r1;
            }
        }
    }
}

extern "C" void kernel_launch(void* const* d_in, const int* in_sizes, int n_in,
                              void* d_out, int out_size, void* d_ws, size_t ws_size,
                              hipStream_t stream)
{
    const float* pts = (const float*)d_in[0];
    const float* W10 = (const float*)d_in[1];
    const float* b10 = (const float*)d_in[2];
    const float* W11 = (const float*)d_in[3];
    const float* b11 = (const float*)d_in[4];
    const float* W12 = (const float*)d_in[5];
    const float* b12 = (const float*)d_in[6];
    const float* W20 = (const float*)d_in[7];
    const float* b20 = (const float*)d_in[8];
    const float* W21 = (const float*)d_in[9];
    const float* b21 = (const float*)d_in[10];
    const int*   x   = (const int*)d_in[11];
    float* out = (float*)d_out;

    // Workspace layout (re-poisoned every call -> rebuild every call):
    char* ws = (char*)d_ws;
    unsigned long long* argBuf = (unsigned long long*)ws;            //  64 KB
    unsigned short* BbWs       = (unsigned short*)(ws + 65536);      //  16 KB
    unsigned short* BcWs       = (unsigned short*)(ws + 81920);      // 128 KB (total 210 KB)

    // Node 1: swizzle weights to MFMA B-frag order + zero argBuf
    k_prep<<<dim3(256), dim3(256), 0, stream>>>(W11, W12, BbWs, BcWs, argBuf);

    // Node 2: big MLP + argmax over 65536 points/case
    k_mlp1_argmax<<<dim3(128, NCASES), dim3(512), 0, stream>>>(
        pts, W10, b10, b11, b12, BbWs, BcWs, argBuf);

    // Node 3: gather + mlp1 over 512 critical pts + max + head + scatter, per case
    k_tail<<<dim3(NCASES), dim3(512), 0, stream>>>(
        pts, argBuf, W10, b10, b11, b12, BbWs, BcWs, W20, b20, W21, b21, x, out);
}